// Round 1
// baseline (318.484 us; speedup 1.0000x reference)
//
#include <hip/hip_runtime.h>

// Problem constants (from reference)
#define VOCAB 32000
#define D     64
#define B     32
#define S     512
#define NCHUNK 8     // number of time chunks
#define CLEN   64    // chunk length (S / NCHUNK)

__device__ __constant__ const float DECAY = 0.9f;  // 1 - 0.1

// ---------------------------------------------------------------------------
// Pass 1: gather content[b,s,:] = emb[x[b,s],:]   (float4 vectorized)
// grid: B*S*(D/4)/256 = 1024 blocks x 256 threads
// ---------------------------------------------------------------------------
__global__ void qmn_gather(const int* __restrict__ x,
                           const float4* __restrict__ emb4,
                           float4* __restrict__ content4) {
    int tid = blockIdx.x * blockDim.x + threadIdx.x;   // [0, B*S*16)
    int bs  = tid >> 4;        // which (b,s) token
    int d4  = tid & 15;        // which float4 of the 64-float row
    int tok = x[bs];
    content4[tid] = emb4[tok * (D / 4) + d4];
}

// ---------------------------------------------------------------------------
// Pass 2: sequential scan per (b,i,j); store rho only at chunk boundaries.
// block: 256 threads = 4 i-rows x 64 j. grid: B*16 = 512 blocks.
// rho starts at identity; recurrence rho = rho*DECAY + c[i]*c[j].
// Boundary for chunk c (c>=1) is the state after step c*CLEN-1.
// ---------------------------------------------------------------------------
__global__ void qmn_boundaries(const float* __restrict__ content,
                               float* __restrict__ bound) {
    int b     = blockIdx.x >> 4;            // 16 blocks per batch
    int iBase = (blockIdx.x & 15) * 4;
    int j     = threadIdx.x & 63;
    int i     = iBase + (threadIdx.x >> 6);

    float rho = (i == j) ? 1.0f : 0.0f;
    const float* cb = content + (size_t)b * S * D;

    for (int t = 0; t < S; ++t) {
        float cj = cb[t * D + j];    // coalesced across lanes
        float ci = cb[t * D + i];    // wave-uniform broadcast
        rho = rho * DECAY + ci * cj;
        int tn = t + 1;
        if ((tn & (CLEN - 1)) == 0 && tn < S) {
            int c = tn >> 6;  // chunk that starts at tn
            bound[(((size_t)b * NCHUNK + c) * D + i) * D + j] = rho;
        }
    }
}

// ---------------------------------------------------------------------------
// Pass 3: replay each chunk from its boundary rho, writing all states.
// block: 256 threads = 16 i-rows x 16 jq (float4 over j).
// grid: B * NCHUNK * 4 = 1024 blocks.
// A wave writes 4 consecutive 256B rows = 1KiB contiguous -> fully coalesced.
// ---------------------------------------------------------------------------
__global__ void qmn_states(const float* __restrict__ content,
                           const float4* __restrict__ bound4,
                           float4* __restrict__ out4) {
    int blk   = blockIdx.x;
    int iBase = (blk & 3) * 16;
    int c     = (blk >> 2) & (NCHUNK - 1);
    int b     = blk >> 5;

    int jq = threadIdx.x & 15;          // float4 index over j
    int i  = iBase + (threadIdx.x >> 4);

    float4 rho;
    if (c == 0) {
        // identity init
        int j0 = jq * 4;
        rho.x = (i == j0 + 0) ? 1.0f : 0.0f;
        rho.y = (i == j0 + 1) ? 1.0f : 0.0f;
        rho.z = (i == j0 + 2) ? 1.0f : 0.0f;
        rho.w = (i == j0 + 3) ? 1.0f : 0.0f;
    } else {
        rho = bound4[(((size_t)b * NCHUNK + c) * D + i) * (D / 4) + jq];
    }

    const float*  cb  = content + ((size_t)b * S + (size_t)c * CLEN) * D;
    const float4* cb4 = (const float4*)cb;

    size_t outBase = ((size_t)b * S + (size_t)c * CLEN) * D;  // in rows of D floats

    #pragma unroll 4
    for (int tt = 0; tt < CLEN; ++tt) {
        float  ci  = cb[tt * D + i];          // wave-group uniform scalar
        float4 cj4 = cb4[tt * (D / 4) + jq];  // coalesced row read
        rho.x = rho.x * DECAY + ci * cj4.x;
        rho.y = rho.y * DECAY + ci * cj4.y;
        rho.z = rho.z * DECAY + ci * cj4.z;
        rho.w = rho.w * DECAY + ci * cj4.w;
        // out[((b*S + t)*D + i)*D + j] as float4
        out4[((outBase + (size_t)tt * D) + i) * (D / 4) + jq] = rho;
    }
}

// ---------------------------------------------------------------------------
// Launch
// ---------------------------------------------------------------------------
extern "C" void kernel_launch(void* const* d_in, const int* in_sizes, int n_in,
                              void* d_out, int out_size, void* d_ws, size_t ws_size,
                              hipStream_t stream) {
    const int*   x   = (const int*)d_in[0];     // [B, S] token ids
    const float* emb = (const float*)d_in[1];   // [VOCAB, D]
    float* out = (float*)d_out;                 // [B, S, D, D]

    // workspace layout: content (B*S*D floats = 4 MiB) | boundaries (B*NCHUNK*D*D = 4 MiB)
    float* content = (float*)d_ws;
    float* bound   = content + (size_t)B * S * D;

    // Pass 1: gather embeddings
    {
        int total = B * S * (D / 4);            // 262144 float4 elements
        qmn_gather<<<total / 256, 256, 0, stream>>>(x, (const float4*)emb,
                                                    (float4*)content);
    }
    // Pass 2: chunk-boundary scan
    qmn_boundaries<<<B * 16, 256, 0, stream>>>(content, bound);

    // Pass 3: per-chunk replay, write all states
    qmn_states<<<B * NCHUNK * 4, 256, 0, stream>>>(content, (const float4*)bound,
                                                   (float4*)out);
}